// Round 14
// baseline (230.234 us; speedup 1.0000x reference)
//
#include <hip/hip_runtime.h>

using half8   = __attribute__((ext_vector_type(8))) _Float16;
using floatx4 = __attribute__((ext_vector_type(4))) float;

constexpr int BATCH = 8, SEQn = 8, CCH = 1024, PPL = 512, HWSZ = 196;
constexpr int LSZ = 1568;            // SEQ * H * W
constexpr int LP  = 1664;            // padded L: 13*128
constexpr float BN_EPS = 1e-5f;
constexpr long TOT = (long)BATCH * SEQn * CCH * HWSZ;  // 12,845,056

// async global->LDS, 16B per lane; lds base must be wave-uniform (HW adds lane*16B)
__device__ __forceinline__ void gload16(const void* g, void* lds) {
    __builtin_amdgcn_global_load_lds(
        (const __attribute__((address_space(1))) unsigned int*)g,
        (__attribute__((address_space(3))) unsigned int*)lds, 16, 0, 0);
}

#define MFMA_(a, b, c) __builtin_amdgcn_mfma_f32_16x16x32_f16((a), (b), (c), 0, 0, 0)
#define VM6 asm volatile("s_waitcnt vmcnt(6)" ::: "memory")
#define VM4 asm volatile("s_waitcnt vmcnt(4)" ::: "memory")
#define VM3 asm volatile("s_waitcnt vmcnt(3)" ::: "memory")
#define VM0 asm volatile("s_waitcnt vmcnt(0)" ::: "memory")

// =====================================================================
// hgemm8: fp16 MFMA GEMM (round-6/8/10/12 proven schedule, FROZEN):
//  tile 256(M) x 128(N), BK=32, 256 threads = 4 waves (2M x 2N),
//  per-wave 128x64 via 8x4 frags of 16x16x32_f16 -> 32 MFMA per K-tile.
//  LDS: 3 bufs x 24KB = 72KB -> 2 blocks/CU. Prefetch distance 2; counted
//  gate vmcnt(6) once per tile (NEVER 0 in main loop — round-7 lesson).
//  Swizzle (rule #21 both-sides, 0 conflicts since round 4):
//   row r granule c holds src chunk c^((r>>1)&3); read slot (ln>>4)^((ln>>1)&3).
//  XCD remap: 1D grid, bz = wid&7 (batch -> XCD; grids %8==0 -> bijective).
// EPI: 0 = tpg projections (G1)
// =====================================================================
template<int EPI>
__global__ __launch_bounds__(256, 2)
void hgemm8(const _Float16* __restrict__ A, long asb, int lda,
            const _Float16* __restrict__ B, long bsb, int ldb,
            void* __restrict__ C0p, long c0s,
            void* __restrict__ C1p, long c1s,
            void* __restrict__ C2p, long c2s,
            const float* __restrict__ bias, int nx, int Mdim, int K)
{
    __shared__ __align__(16) _Float16 sh[36864];   // 72KB: 3 bufs x 12288 halfs
    const int wid = blockIdx.x;
    const int bz  = wid & 7;
    const int rr  = wid >> 3;
    const int bx  = rr % nx;
    const int by  = rr / nx;

    const _Float16* Ab = A + (long)bz * asb;
    const _Float16* Bb = B + (long)bz * bsb;
    int m0 = by * 256;
    if (m0 + 256 > Mdim) m0 = Mdim - 256;          // overlapped last M-tile
    const int n0 = bx * 128;
    const int tid = threadIdx.x;
    const int w = tid >> 6, ln = tid & 63;
    const int wm = w >> 1, wn = w & 1;

    const int srow = tid >> 2;                       // 0..63 row within issue
    const int schunk = (tid & 3) ^ ((tid >> 3) & 3); // src chunk = dest ^ f(row)
    const _Float16* pA = Ab + (long)(m0 + srow) * lda + schunk * 8;
    const _Float16* pB = Bb + (long)(n0 + srow) * ldb + schunk * 8;
    const long lda64 = (long)64 * lda, ldb64 = (long)64 * ldb;
    const int sdw = w * 512;                         // wave-uniform dest (halfs)

    const int soff = ((ln >> 4) ^ ((ln >> 1) & 3)) * 8;
    int aoff[8], boff[4];
    #pragma unroll
    for (int mi = 0; mi < 8; ++mi)
        aoff[mi] = (wm * 128 + mi * 16 + (ln & 15)) * 32 + soff;
    #pragma unroll
    for (int ni = 0; ni < 4; ++ni)
        boff[ni] = 8192 + (wn * 64 + ni * 16 + (ln & 15)) * 32 + soff;

    floatx4 acc[8][4];
    #pragma unroll
    for (int i = 0; i < 8; ++i)
        #pragma unroll
        for (int j = 0; j < 4; ++j) acc[i][j] = (floatx4){0.f, 0.f, 0.f, 0.f};

    const int NT = K >> 5;      // BK=32

#define TILE(ISSUES, GATE)                                                   \
  {                                                                          \
    half8 af[8], bf[4];                                                      \
    _Pragma("unroll")                                                        \
    for (int mi = 0; mi < 8; ++mi)                                           \
        af[mi] = *(const half8*)&sh[cur + aoff[mi]];                         \
    _Pragma("unroll")                                                        \
    for (int ni = 0; ni < 4; ++ni)                                           \
        bf[ni] = *(const half8*)&sh[cur + boff[ni]];                         \
    ISSUES                                                                   \
    __builtin_amdgcn_sched_barrier(0);                                       \
    __builtin_amdgcn_s_barrier();                                            \
    asm volatile("s_waitcnt lgkmcnt(0)" ::: "memory");                       \
    __builtin_amdgcn_sched_barrier(0);                                       \
    __builtin_amdgcn_s_setprio(1);                                           \
    _Pragma("unroll")                                                        \
    for (int ni = 0; ni < 4; ++ni)                                           \
        _Pragma("unroll")                                                    \
        for (int mi = 0; mi < 8; ++mi)                                       \
            acc[mi][ni] = MFMA_(af[mi], bf[ni], acc[mi][ni]);                \
    __builtin_amdgcn_s_setprio(0);                                           \
    __builtin_amdgcn_sched_barrier(0);                                       \
    GATE;                                                                    \
    __builtin_amdgcn_s_barrier();                                            \
    __builtin_amdgcn_sched_barrier(0);                                       \
  }

    // ---- prologue: stage tile0 -> buf0, tile1 -> buf1 ----
    #pragma unroll
    for (int i = 0; i < 4; ++i) gload16(pA + i * lda64, &sh[i * 2048 + sdw]);
    #pragma unroll
    for (int i = 0; i < 2; ++i) gload16(pB + i * ldb64, &sh[8192 + i * 2048 + sdw]);
    #pragma unroll
    for (int i = 0; i < 4; ++i) gload16(pA + 32 + i * lda64, &sh[12288 + i * 2048 + sdw]);
    #pragma unroll
    for (int i = 0; i < 2; ++i) gload16(pB + 32 + i * ldb64, &sh[20480 + i * 2048 + sdw]);
    VM6;   // t0's 6 done; t1's 6 in flight
    __builtin_amdgcn_sched_barrier(0);
    __builtin_amdgcn_s_barrier();
    __builtin_amdgcn_sched_barrier(0);

    int cur = 0, nxt = 12288, stg = 24576;
    const _Float16* pA_s = pA + 64;
    const _Float16* pB_s = pB + 64;

    // ---- main loop: compute tile t, stage tile t+2 into stg ----
    for (int t = 0; t < NT - 2; ++t) {
        TILE(
           gload16(pA_s,             &sh[stg + sdw]);
           gload16(pA_s + lda64,     &sh[stg + 2048 + sdw]);
           gload16(pA_s + 2 * lda64, &sh[stg + 4096 + sdw]);
           gload16(pA_s + 3 * lda64, &sh[stg + 6144 + sdw]);
           gload16(pB_s,             &sh[stg + 8192 + sdw]);
           gload16(pB_s + ldb64,     &sh[stg + 10240 + sdw]);, VM6)
        const int tmp = cur; cur = nxt; nxt = stg; stg = tmp;
        pA_s += 32; pB_s += 32;
    }
    // ---- tail: tile NT-2 (drain all), tile NT-1 ----
    TILE(, VM0)
    { const int tmp = cur; cur = nxt; nxt = stg; stg = tmp; }
    TILE(, )
#undef TILE
    __builtin_amdgcn_sched_barrier(0);

    // ---- epilogue: C/D layout col = ln&15, row = (ln>>4)*4 + reg ----
    const int cm = wm * 128 + (ln >> 4) * 4;
    const int cn = wn * 64 + (ln & 15);

    if constexpr (EPI == 0) {
        if (m0 < 1024) {   // t or p -> transposed store [L, 512]
            _Float16* T = (_Float16*)C0p + (long)bz * c0s
                          + (m0 >= 512 ? (long)LP * PPL : 0);
            const int mb = m0 & 511;
            #pragma unroll
            for (int mi = 0; mi < 8; ++mi) {
                const int gmF = m0 + cm + mi * 16;
                const float4 bv = *(const float4*)&bias[gmF];
                const int gm = mb + cm + mi * 16;
                #pragma unroll
                for (int ni = 0; ni < 4; ++ni) {
                    const int gn = n0 + cn + ni * 16;
                    union { _Float16 h[4]; uint2 u; } pk;
                    pk.h[0] = (_Float16)(acc[mi][ni][0] + bv.x);
                    pk.h[1] = (_Float16)(acc[mi][ni][1] + bv.y);
                    pk.h[2] = (_Float16)(acc[mi][ni][2] + bv.z);
                    pk.h[3] = (_Float16)(acc[mi][ni][3] + bv.w);
                    *(uint2*)&T[(long)gn * PPL + gm] = pk.u;
                }
            }
        } else {           // g: normal [512, LP] + transposed into gx2T
            _Float16* G  = (_Float16*)C1p + (long)bz * c1s;
            _Float16* GT = (_Float16*)C2p + (long)bz * c2s;
            #pragma unroll
            for (int mi = 0; mi < 8; ++mi) {
                const int gmF = m0 + cm + mi * 16;
                const float4 bv = *(const float4*)&bias[gmF];
                const int q = gmF - 1024;
                #pragma unroll
                for (int ni = 0; ni < 4; ++ni) {
                    const int gn = n0 + cn + ni * 16;
                    union { _Float16 h[4]; uint2 u; } pk;
                    pk.h[0] = (_Float16)(acc[mi][ni][0] + bv.x);
                    pk.h[1] = (_Float16)(acc[mi][ni][1] + bv.y);
                    pk.h[2] = (_Float16)(acc[mi][ni][2] + bv.z);
                    pk.h[3] = (_Float16)(acc[mi][ni][3] + bv.w);
                    *(uint2*)&GT[(long)gn * 1024 + q] = pk.u;
                    const bool ok = gn < LSZ;   // keep pad cols of g zero
                    G[(long)(q + 0) * LP + gn] = ok ? pk.h[0] : (_Float16)0.f;
                    G[(long)(q + 1) * LP + gn] = ok ? pk.h[1] : (_Float16)0.f;
                    G[(long)(q + 2) * LP + gn] = ok ? pk.h[2] : (_Float16)0.f;
                    G[(long)(q + 3) * LP + gn] = ok ? pk.h[3] : (_Float16)0.f;
                }
            }
        }
    }
}

// =====================================================================
// hgemm8w: 8-wave variant (round-13, kept for G2 — neutral-to-positive):
//  same 256x128 tile / 72KB 3-buf / counted-vmcnt schedule, 512 threads =
//  8 waves (4M x 2N), per-wave 64x64. 2 blocks/CU -> 4 waves/SIMD.
//  Gate vmcnt(3); tail drains 0. Emits att fp16.
// =====================================================================
__global__ __launch_bounds__(512, 4)
void hgemm8w(const _Float16* __restrict__ A, long asb, int lda,
             const _Float16* __restrict__ B, long bsb, int ldb,
             void* __restrict__ C0p, long c0s, int nx, int Mdim, int K)
{
    __shared__ __align__(16) _Float16 sh[36864];   // 72KB: 3 bufs x 12288 halfs
    const int wid = blockIdx.x;
    const int bz  = wid & 7;
    const int rr  = wid >> 3;
    const int bx  = rr % nx;
    const int by  = rr / nx;

    const _Float16* Ab = A + (long)bz * asb;
    const _Float16* Bb = B + (long)bz * bsb;
    int m0 = by * 256;
    if (m0 + 256 > Mdim) m0 = Mdim - 256;
    const int n0 = bx * 128;
    const int tid = threadIdx.x;
    const int w = tid >> 6, ln = tid & 63;
    const int wm = w >> 1, wn = w & 1;             // 4M x 2N

    const int srow = tid >> 2;                       // 0..127
    const int schunk = (tid & 3) ^ ((tid >> 3) & 3); // dest ^ f(row)
    const _Float16* pA = Ab + (long)(m0 + srow) * lda + schunk * 8;
    const _Float16* pB = Bb + (long)(n0 + srow) * ldb + schunk * 8;
    const long lda128 = (long)128 * lda;
    const int sdw = w * 512;                         // wave-uniform dest (halfs)

    const int soff = ((ln >> 4) ^ ((ln >> 1) & 3)) * 8;
    int aoff[4], boff[4];
    #pragma unroll
    for (int mi = 0; mi < 4; ++mi)
        aoff[mi] = (wm * 64 + mi * 16 + (ln & 15)) * 32 + soff;
    #pragma unroll
    for (int ni = 0; ni < 4; ++ni)
        boff[ni] = 8192 + (wn * 64 + ni * 16 + (ln & 15)) * 32 + soff;

    floatx4 acc[4][4];
    #pragma unroll
    for (int i = 0; i < 4; ++i)
        #pragma unroll
        for (int j = 0; j < 4; ++j) acc[i][j] = (floatx4){0.f, 0.f, 0.f, 0.f};

    const int NT = K >> 5;

#define STG3(koff, BASE)                                                     \
    gload16(pA + (koff),          &sh[(BASE) + sdw]);                        \
    gload16(pA + (koff) + lda128, &sh[(BASE) + 4096 + sdw]);                 \
    gload16(pB + (koff),          &sh[(BASE) + 8192 + sdw]);

#define TILEW(ISSUES, GATE)                                                  \
  {                                                                          \
    half8 af[4], bf[4];                                                      \
    _Pragma("unroll")                                                        \
    for (int mi = 0; mi < 4; ++mi)                                           \
        af[mi] = *(const half8*)&sh[cur + aoff[mi]];                         \
    _Pragma("unroll")                                                        \
    for (int ni = 0; ni < 4; ++ni)                                           \
        bf[ni] = *(const half8*)&sh[cur + boff[ni]];                         \
    ISSUES                                                                   \
    __builtin_amdgcn_sched_barrier(0);                                       \
    __builtin_amdgcn_s_barrier();                                            \
    asm volatile("s_waitcnt lgkmcnt(0)" ::: "memory");                       \
    __builtin_amdgcn_sched_barrier(0);                                       \
    __builtin_amdgcn_s_setprio(1);                                           \
    _Pragma("unroll")                                                        \
    for (int ni = 0; ni < 4; ++ni)                                           \
        _Pragma("unroll")                                                    \
        for (int mi = 0; mi < 4; ++mi)                                       \
            acc[mi][ni] = MFMA_(af[mi], bf[ni], acc[mi][ni]);                \
    __builtin_amdgcn_s_setprio(0);                                           \
    __builtin_amdgcn_sched_barrier(0);                                       \
    GATE;                                                                    \
    __builtin_amdgcn_s_barrier();                                            \
    __builtin_amdgcn_sched_barrier(0);                                       \
  }

    STG3(0, 0)
    STG3(32, 12288)
    VM3;
    __builtin_amdgcn_sched_barrier(0);
    __builtin_amdgcn_s_barrier();
    __builtin_amdgcn_sched_barrier(0);

    int cur = 0, nxt = 12288, stg = 24576;

    for (int t = 0; t < NT - 2; ++t) {
        TILEW(STG3((t + 2) * 32, stg), VM3)
        const int tmp = cur; cur = nxt; nxt = stg; stg = tmp;
    }
    TILEW(, VM0)
    { const int tmp = cur; cur = nxt; nxt = stg; stg = tmp; }
    TILEW(, )
#undef TILEW
#undef STG3
    __builtin_amdgcn_sched_barrier(0);

    // ---- epilogue: att fp16 [LP halfs pitch] ----
    const int cm = wm * 64 + (ln >> 4) * 4;
    const int cn = wn * 64 + (ln & 15);
    _Float16* C = (_Float16*)C0p + (long)bz * c0s;
    #pragma unroll
    for (int mi = 0; mi < 4; ++mi) {
        const int gm = m0 + cm + mi * 16;
        #pragma unroll
        for (int ni = 0; ni < 4; ++ni) {
            const int gn = n0 + cn + ni * 16;
            #pragma unroll
            for (int j = 0; j < 4; ++j)
                C[(long)(gm + j) * LP + gn] = (_Float16)acc[mi][ni][j];
        }
    }
}

// =====================================================================
// hgemm128<EPI>: 128x128-tile GEMM (round-8/12 proven schedule).
//  3 bufs x 16KB = 48KB -> 3 blocks/CU; vmcnt(4) counted gate.
//  Round 14: templated epilogue —
//   EPI 2 = x2T fp16 into gx2T[:, 512:1024] (G3, K=1568)
//   EPI 3 = y fp16 + bias, pitch LP (G4: 832 blocks / 768 slots = 1.08
//           balanced rounds vs hgemm8's 416/512 = unbalanced 2-block tail)
// =====================================================================
template<int EPI>
__global__ __launch_bounds__(256, 3)
void hgemm128(const _Float16* __restrict__ A, long asb, int lda,
              const _Float16* __restrict__ B, long bsb, int ldb,
              void* __restrict__ C0p, long c0s,
              const float* __restrict__ bias, int nx, int K)
{
    __shared__ __align__(16) _Float16 sh[24576];   // 48KB: 3 bufs x 8192 halfs
    const int wid = blockIdx.x;
    const int bz  = wid & 7;
    const int rr  = wid >> 3;
    const int bx  = rr % nx;
    const int by  = rr / nx;

    const _Float16* Ab = A + (long)bz * asb;
    const _Float16* Bb = B + (long)bz * bsb;
    const int m0 = by * 128;
    const int n0 = bx * 128;
    const int tid = threadIdx.x;
    const int w = tid >> 6, ln = tid & 63;
    const int wm = w >> 1, wn = w & 1;

    const int srow = tid >> 2;
    const int schunk = (tid & 3) ^ ((tid >> 3) & 3);
    const _Float16* pA = Ab + (long)(m0 + srow) * lda + schunk * 8;
    const _Float16* pB = Bb + (long)(n0 + srow) * ldb + schunk * 8;
    const long lda64 = (long)64 * lda, ldb64 = (long)64 * ldb;
    const int sdw = w * 512;

    const int soff = ((ln >> 4) ^ ((ln >> 1) & 3)) * 8;
    int aoff[4], boff[4];
    #pragma unroll
    for (int mi = 0; mi < 4; ++mi)
        aoff[mi] = (wm * 64 + mi * 16 + (ln & 15)) * 32 + soff;
    #pragma unroll
    for (int ni = 0; ni < 4; ++ni)
        boff[ni] = 4096 + (wn * 64 + ni * 16 + (ln & 15)) * 32 + soff;

    floatx4 acc[4][4];
    #pragma unroll
    for (int i = 0; i < 4; ++i)
        #pragma unroll
        for (int j = 0; j < 4; ++j) acc[i][j] = (floatx4){0.f, 0.f, 0.f, 0.f};

    const int NT = K >> 5;   // 49 (G3) or 32 (G4)

#define TILE1(ISSUES, GATE)                                                  \
  {                                                                          \
    half8 af[4], bf[4];                                                      \
    _Pragma("unroll")                                                        \
    for (int mi = 0; mi < 4; ++mi)                                           \
        af[mi] = *(const half8*)&sh[cur + aoff[mi]];                         \
    _Pragma("unroll")                                                        \
    for (int ni = 0; ni < 4; ++ni)                                           \
        bf[ni] = *(const half8*)&sh[cur + boff[ni]];                         \
    ISSUES                                                                   \
    __builtin_amdgcn_sched_barrier(0);                                       \
    __builtin_amdgcn_s_barrier();                                            \
    asm volatile("s_waitcnt lgkmcnt(0)" ::: "memory");                       \
    __builtin_amdgcn_sched_barrier(0);                                       \
    __builtin_amdgcn_s_setprio(1);                                           \
    _Pragma("unroll")                                                        \
    for (int ni = 0; ni < 4; ++ni)                                           \
        _Pragma("unroll")                                                    \
        for (int mi = 0; mi < 4; ++mi)                                       \
            acc[mi][ni] = MFMA_(af[mi], bf[ni], acc[mi][ni]);                \
    __builtin_amdgcn_s_setprio(0);                                           \
    __builtin_amdgcn_sched_barrier(0);                                       \
    GATE;                                                                    \
    __builtin_amdgcn_s_barrier();                                            \
    __builtin_amdgcn_sched_barrier(0);                                       \
  }

    // ---- prologue: stage tile0 -> buf0, tile1 -> buf1 (4 issues each) ----
    gload16(pA,              &sh[sdw]);
    gload16(pA + lda64,      &sh[2048 + sdw]);
    gload16(pB,              &sh[4096 + sdw]);
    gload16(pB + ldb64,      &sh[6144 + sdw]);
    gload16(pA + 32,         &sh[8192 + sdw]);
    gload16(pA + 32 + lda64, &sh[10240 + sdw]);
    gload16(pB + 32,         &sh[12288 + sdw]);
    gload16(pB + 32 + ldb64, &sh[14336 + sdw]);
    VM4;   // t0's 4 done; t1's 4 in flight
    __builtin_amdgcn_sched_barrier(0);
    __builtin_amdgcn_s_barrier();
    __builtin_amdgcn_sched_barrier(0);

    int cur = 0, nxt = 8192, stg = 16384;
    const _Float16* pA_s = pA + 64;
    const _Float16* pB_s = pB + 64;

    for (int t = 0; t < NT - 2; ++t) {
        TILE1(
           gload16(pA_s,         &sh[stg + sdw]);
           gload16(pA_s + lda64, &sh[stg + 2048 + sdw]);
           gload16(pB_s,         &sh[stg + 4096 + sdw]);
           gload16(pB_s + ldb64, &sh[stg + 6144 + sdw]);, VM4)
        const int tmp = cur; cur = nxt; nxt = stg; stg = tmp;
        pA_s += 32; pB_s += 32;
    }
    TILE1(, VM0)
    { const int tmp = cur; cur = nxt; nxt = stg; stg = tmp; }
    TILE1(, )
#undef TILE1
    __builtin_amdgcn_sched_barrier(0);

    const int cm = wm * 64 + (ln >> 4) * 4;
    const int cn = wn * 64 + (ln & 15);
    if constexpr (EPI == 2) {          // x2T fp16 into gx2T[:, 512:1024]
        _Float16* C = (_Float16*)C0p + (long)bz * c0s + 512;
        #pragma unroll
        for (int mi = 0; mi < 4; ++mi) {
            const int gm = m0 + cm + mi * 16;
            #pragma unroll
            for (int ni = 0; ni < 4; ++ni) {
                const int gn = n0 + cn + ni * 16;
                #pragma unroll
                for (int j = 0; j < 4; ++j)
                    C[(long)(gm + j) * 1024 + gn] = (_Float16)acc[mi][ni][j];
            }
        }
    } else {                           // EPI 3: y fp16 + bias, pitch LP
        _Float16* C = (_Float16*)C0p + (long)bz * c0s;
        #pragma unroll
        for (int mi = 0; mi < 4; ++mi) {
            const int gmF = m0 + cm + mi * 16;
            const float4 bv = *(const float4*)&bias[gmF];
            #pragma unroll
            for (int ni = 0; ni < 4; ++ni) {
                const int gn = n0 + cn + ni * 16;
                C[(long)(gmF + 0) * LP + gn] = (_Float16)(acc[mi][ni][0] + bv.x);
                C[(long)(gmF + 1) * LP + gn] = (_Float16)(acc[mi][ni][1] + bv.y);
                C[(long)(gmF + 2) * LP + gn] = (_Float16)(acc[mi][ni][2] + bv.z);
                C[(long)(gmF + 3) * LP + gn] = (_Float16)(acc[mi][ni][3] + bv.w);
            }
        }
    }
}

// ---- weight converts ----
__global__ void conv_wtpg(const float* __restrict__ tw, const float* __restrict__ pw,
                          const float* __restrict__ gw, const float* __restrict__ tb,
                          const float* __restrict__ pb, const float* __restrict__ gb,
                          _Float16* __restrict__ W, float* __restrict__ btpg)
{
    const int i = blockIdx.x * 256 + threadIdx.x;     // float4 groups
    if (i < 393216) {
        const int e = i * 4;
        const int sz = 512 * 1024;
        const float* src = (e < sz) ? tw + e : ((e < 2 * sz) ? pw + e - sz : gw + e - 2 * sz);
        const float4 v = *(const float4*)src;
        union { _Float16 h[4]; uint2 u; } pk;
        pk.h[0] = (_Float16)v.x; pk.h[1] = (_Float16)v.y;
        pk.h[2] = (_Float16)v.z; pk.h[3] = (_Float16)v.w;
        *(uint2*)&W[e] = pk.u;
    }
    if (i < 512) btpg[i] = tb[i];
    else if (i < 1024) btpg[i] = pb[i - 512];
    else if (i < 1536) btpg[i] = gb[i - 1024];
}

__global__ void conv_wcat(const float* __restrict__ w1, const float* __restrict__ w2,
                          const float* __restrict__ b1, const float* __restrict__ b2,
                          _Float16* __restrict__ W, float* __restrict__ bsum)
{
    const int i = blockIdx.x * 256 + threadIdx.x;     // float4 groups
    if (i < 262144) {
        const int e = i * 4;
        const int c = e >> 10, k = e & 1023;
        const float* src = (k < 512) ? (w1 + c * 512 + k) : (w2 + c * 512 + k - 512);
        const float4 v = *(const float4*)src;
        union { _Float16 h[4]; uint2 u; } pk;
        pk.h[0] = (_Float16)v.x; pk.h[1] = (_Float16)v.y;
        pk.h[2] = (_Float16)v.z; pk.h[3] = (_Float16)v.w;
        *(uint2*)&W[e] = pk.u;
    }
    if (i < 1024) bsum[i] = b1[i] + b2[i];
}

// ---- x [b*8+n][c][hw] fp32 -> xtT [b][l=n*196+hw][c] fp16, LDS transpose ----
__global__ __launch_bounds__(256) void transpose_x(const float* __restrict__ x,
                                                   _Float16* __restrict__ xtT)
{
    __shared__ _Float16 t[128 * 201];
    const int cs = blockIdx.x * 128;
    const int n = blockIdx.y, b = blockIdx.z;
    const float* src = x + ((long)(b * 8 + n) * 1024 + cs) * 196;
    for (int i = threadIdx.x; i < 128 * 49; i += 256) {
        const int r = i / 49, ch = i % 49;
        const float4 v = *(const float4*)&src[r * 196 + ch * 4];
        _Float16* tp = &t[r * 201 + ch * 4];
        tp[0] = (_Float16)v.x; tp[1] = (_Float16)v.y;
        tp[2] = (_Float16)v.z; tp[3] = (_Float16)v.w;
    }
    __syncthreads();
    _Float16* dst = xtT + (long)b * LP * 1024 + (long)n * 196 * 1024 + cs;
    for (int i = threadIdx.x; i < 196 * 16; i += 256) {
        const int hw = i >> 4, cg = i & 15;
        union { _Float16 h[8]; uint4 u; } pk;
        #pragma unroll
        for (int j = 0; j < 8; ++j) pk.h[j] = t[(cg * 8 + j) * 201 + hw];
        *(uint4*)&dst[(long)hw * 1024 + cg * 8] = pk.u;
    }
}

// ---- softmax: att fp16 rows in place, half8-vectorized; zero-pad K-tail ----
__global__ __launch_bounds__(256) void softmax_rows(_Float16* __restrict__ att)
{
    const int blk = blockIdx.x;
    const int b = blk / LSZ, r = blk % LSZ;
    _Float16* row = att + (long)b * LP * LP + (long)r * LP;
    const int tid = threadIdx.x;
    const bool act = tid < 196;

    float v[8];
    float mx = -1e30f;
    if (act) {
        const half8 h = *(const half8*)&row[tid * 8];
        #pragma unroll
        for (int j = 0; j < 8; ++j) { v[j] = (float)h[j]; mx = fmaxf(mx, v[j]); }
    }
    __shared__ float red[256];
    red[tid] = mx; __syncthreads();
    for (int s = 128; s > 0; s >>= 1) {
        if (tid < s) red[tid] = fmaxf(red[tid], red[tid + s]);
        __syncthreads();
    }
    mx = red[0]; __syncthreads();

    float sum = 0.0f;
    if (act) {
        #pragma unroll
        for (int j = 0; j < 8; ++j) { v[j] = __expf(v[j] - mx); sum += v[j]; }
    }
    red[tid] = sum; __syncthreads();
    for (int s = 128; s > 0; s >>= 1) {
        if (tid < s) red[tid] += red[tid + s];
        __syncthreads();
    }
    const float inv = 1.0f / red[0];
    if (act) {
        union { _Float16 h[8]; uint4 u; } pk;
        #pragma unroll
        for (int j = 0; j < 8; ++j) pk.h[j] = (_Float16)(v[j] * inv);
        *(uint4*)&row[tid * 8] = pk.u;
    } else if (tid < 208) {
        union { _Float16 h[8]; uint4 u; } pk;
        #pragma unroll
        for (int j = 0; j < 8; ++j) pk.h[j] = (_Float16)0.f;
        *(uint4*)&row[tid * 8] = pk.u;
    }
}

// ---- BN stats per channel over (b, l<1568) from y fp16 [1024, LP] ----
__global__ __launch_bounds__(256)
void bn_stats(const _Float16* __restrict__ y, const float* __restrict__ gamma,
              const float* __restrict__ beta, float* __restrict__ scale,
              float* __restrict__ shift)
{
    const int c = blockIdx.x;
    const int tid = threadIdx.x;
    float s1 = 0.f, s2 = 0.f;
    for (int idx = tid; idx < 8 * 196; idx += 256) {
        const int b = idx / 196, ch = idx % 196;
        const half8 v = *(const half8*)&y[(long)b * CCH * LP + (long)c * LP + ch * 8];
        #pragma unroll
        for (int j = 0; j < 8; ++j) { const float t = (float)v[j]; s1 += t; s2 += t * t; }
    }
    __shared__ float r1[256], r2[256];
    r1[tid] = s1; r2[tid] = s2; __syncthreads();
    for (int s = 128; s > 0; s >>= 1) {
        if (tid < s) { r1[tid] += r1[tid + s]; r2[tid] += r2[tid + s]; }
        __syncthreads();
    }
    if (tid == 0) {
        const float cnt = (float)(BATCH * LSZ);
        const float mean = r1[0] / cnt;
        const float var  = r2[0] / cnt - mean * mean;
        const float istd = rsqrtf(var + BN_EPS);
        const float sc = gamma[c] * istd;
        scale[c] = sc;
        shift[c] = beta[c] - mean * sc;
    }
}

// ---- out[b,n,c,hw] = y[b,c,n*196+hw]*scale[c]+shift[c] + x[b,n,c,hw] ----
__global__ void epilogue_k(const _Float16* __restrict__ y, const float* __restrict__ x,
                           const float* __restrict__ scale, const float* __restrict__ shift,
                           float* __restrict__ out)
{
    const long i4 = (long)blockIdx.x * 256 + threadIdx.x;
    const long idx = i4 * 4;
    if (idx >= TOT) return;
    const int b  = (int)(idx / ((long)SEQn * CCH * HWSZ));
    const int r  = (int)(idx % ((long)SEQn * CCH * HWSZ));
    const int n  = r / (CCH * HWSZ);
    const int r2 = r % (CCH * HWSZ);
    const int c  = r2 / HWSZ;
    const int hw = r2 % HWSZ;
    union { _Float16 h[4]; uint2 u; } v;
    v.u = *(const uint2*)&y[(long)b * CCH * LP + (long)c * LP + n * 196 + hw];
    const float4 xv = *(const float4*)&x[idx];
    const float sc = scale[c], sh = shift[c];
    float4 o;
    o.x = (float)v.h[0] * sc + sh + xv.x;
    o.y = (float)v.h[1] * sc + sh + xv.y;
    o.z = (float)v.h[2] * sc + sh + xv.z;
    o.w = (float)v.h[3] * sc + sh + xv.w;
    *(float4*)&out[idx] = o;
}

extern "C" void kernel_launch(void* const* d_in, const int* in_sizes, int n_in,
                              void* d_out, int out_size, void* d_ws, size_t ws_size,
                              hipStream_t stream)
{
    const float* x     = (const float*)d_in[0];
    const float* t_w   = (const float*)d_in[1];
    const float* t_b   = (const float*)d_in[2];
    const float* p_w   = (const float*)d_in[3];
    const float* p_b   = (const float*)d_in[4];
    const float* g_w   = (const float*)d_in[5];
    const float* g_b   = (const float*)d_in[6];
    const float* w1_w  = (const float*)d_in[7];
    const float* w1_b  = (const float*)d_in[8];
    const float* w2_w  = (const float*)d_in[9];
    const float* w2_b  = (const float*)d_in[10];
    const float* gamma = (const float*)d_in[11];
    const float* beta  = (const float*)d_in[12];
    float* out = (float*)d_out;

    // ---- workspace layout ----
    char* wsp = (char*)d_ws;
    _Float16* Wtpg = (_Float16*)wsp;                 wsp += (long)1536 * 1024 * 2;
    _Float16* Wcat = (_Float16*)wsp;                 wsp += (long)1024 * 1024 * 2;
    float*    btpg = (float*)wsp;                    wsp += 8192;
    float*    bsum = (float*)wsp;                    wsp += 4096;
    float*    scale= (float*)wsp;                    wsp += 4096;
    float*    shift= (float*)wsp;                    wsp += 4096;
    _Float16* xtT  = (_Float16*)wsp;                 wsp += (long)BATCH * LP * 1024 * 2;
    _Float16* tTpT = (_Float16*)wsp;                 wsp += (long)BATCH * 2 * LP * 512 * 2;
    _Float16* g    = (_Float16*)wsp;                 wsp += (long)BATCH * 512 * LP * 2;
    _Float16* gx2T = (_Float16*)wsp;                 wsp += (long)BATCH * LP * 1024 * 2;
    _Float16* att  = (_Float16*)wsp;                 wsp += (long)BATCH * LP * LP * 2;
    _Float16* y    = xtT;    // alias: xtT dead after G1, G4 runs after

    const long sXT  = (long)LP * 1024;     // xtT / gx2T per-batch (halfs)
    const long sTP  = (long)2 * LP * 512;  // tTpT per-batch
    const long sG   = (long)512 * LP;
    const long sATT = (long)LP * LP;       // att per-batch (halfs)
    const long sY   = (long)CCH * LP;

    // 1) weight converts
    conv_wtpg<<<1536, 256, 0, stream>>>(t_w, p_w, g_w, t_b, p_b, g_b, Wtpg, btpg);
    conv_wcat<<<1024, 256, 0, stream>>>(w1_w, w2_w, w1_b, w2_b, Wcat, bsum);
    // 2) x -> xtT [b, l, c] fp16
    transpose_x<<<dim3(8, 8, 8), 256, 0, stream>>>(x, xtT);
    // 3) tpg projections: M=1536 (6), N=1664 (13), K=1024; grid 624 = 78x8
    hgemm8<0><<<624, 256, 0, stream>>>(
        Wtpg, 0, 1024, xtT, sXT, 1024,
        tTpT, sTP, g, sG, gx2T, sXT, btpg, 13, 1536, 1024);
    // 4) att = tT @ pT^T (fp16 out): 8-wave variant, M=1664, N=1664, K=512
    hgemm8w<<<728, 512, 0, stream>>>(
        tTpT, sTP, 512, tTpT + (long)LP * 512, sTP, 512,
        att, sATT, 13, LP, 512);
    // 5) softmax rows (fp16 in place, zero-pad K-tail)
    softmax_rows<<<BATCH * LSZ, 256, 0, stream>>>(att);
    // 6) x2T[l,q] = sum_{m<1568} att[l,m] g[q,m]: M=1664 (13), N=512 (4), K=1568
    hgemm128<2><<<416, 256, 0, stream>>>(
        att, sATT, LP, g, sG, LP,
        gx2T, sXT, nullptr, 4, 1568);
    // 7) y = [W1|W2] @ [gT|x2T]^T + (b1+b2): ROUND-14 A/B — 128x128 tiles,
    //    M=1024 (8), N=1664 (13), K=1024; grid 832 = 104x8, 3 blocks/CU
    hgemm128<3><<<832, 256, 0, stream>>>(
        Wcat, 0, 1024, gx2T, sXT, 1024,
        y, sY, bsum, 13, 1024);
    // 8) BN stats
    bn_stats<<<CCH, 256, 0, stream>>>(y, gamma, beta, scale, shift);
    // 9) BN apply + residual + layout restore
    epilogue_k<<<(int)(TOT / 4 / 256), 256, 0, stream>>>(y, x, scale, shift, out);
}

// Round 15
// 225.626 us; speedup vs baseline: 1.0204x; 1.0204x over previous
//
#include <hip/hip_runtime.h>

using half8   = __attribute__((ext_vector_type(8))) _Float16;
using floatx4 = __attribute__((ext_vector_type(4))) float;

constexpr int BATCH = 8, SEQn = 8, CCH = 1024, PPL = 512, HWSZ = 196;
constexpr int LSZ = 1568;            // SEQ * H * W
constexpr int LP  = 1664;            // padded L: 13*128
constexpr float BN_EPS = 1e-5f;
constexpr long TOT = (long)BATCH * SEQn * CCH * HWSZ;  // 12,845,056

// async global->LDS, 16B per lane; lds base must be wave-uniform (HW adds lane*16B)
__device__ __forceinline__ void gload16(const void* g, void* lds) {
    __builtin_amdgcn_global_load_lds(
        (const __attribute__((address_space(1))) unsigned int*)g,
        (__attribute__((address_space(3))) unsigned int*)lds, 16, 0, 0);
}

#define MFMA_(a, b, c) __builtin_amdgcn_mfma_f32_16x16x32_f16((a), (b), (c), 0, 0, 0)
#define VM6 asm volatile("s_waitcnt vmcnt(6)" ::: "memory")
#define VM4 asm volatile("s_waitcnt vmcnt(4)" ::: "memory")
#define VM3 asm volatile("s_waitcnt vmcnt(3)" ::: "memory")
#define VM0 asm volatile("s_waitcnt vmcnt(0)" ::: "memory")

// =====================================================================
// hgemm8: fp16 MFMA GEMM (round-6/8/10/12 proven schedule, FROZEN):
//  tile 256(M) x 128(N), BK=32, 256 threads = 4 waves (2M x 2N),
//  per-wave 128x64 via 8x4 frags of 16x16x32_f16 -> 32 MFMA per K-tile.
//  LDS: 3 bufs x 24KB = 72KB -> 2 blocks/CU. Prefetch distance 2; counted
//  gate vmcnt(6) once per tile (NEVER 0 in main loop — round-7 lesson).
//  Swizzle (rule #21 both-sides, 0 conflicts since round 4):
//   row r granule c holds src chunk c^((r>>1)&3); read slot (ln>>4)^((ln>>1)&3).
//  XCD remap: 1D grid, bz = wid&7 (batch -> XCD; grids %8==0 -> bijective).
//  Round 15: exact round-13 config restored (best: 226.5µs). Round-14's
//  hgemm128-on-G4 regressed (+4µs: 128-tile per-flop staging overhead >
//  grid-balance gain) — G4 back on hgemm8<3>.
// EPI: 0 = tpg projections (G1), 3 = y + bias (G4)
// =====================================================================
template<int EPI>
__global__ __launch_bounds__(256, 2)
void hgemm8(const _Float16* __restrict__ A, long asb, int lda,
            const _Float16* __restrict__ B, long bsb, int ldb,
            void* __restrict__ C0p, long c0s,
            void* __restrict__ C1p, long c1s,
            void* __restrict__ C2p, long c2s,
            const float* __restrict__ bias, int nx, int Mdim, int K)
{
    __shared__ __align__(16) _Float16 sh[36864];   // 72KB: 3 bufs x 12288 halfs
    const int wid = blockIdx.x;
    const int bz  = wid & 7;
    const int rr  = wid >> 3;
    const int bx  = rr % nx;
    const int by  = rr / nx;

    const _Float16* Ab = A + (long)bz * asb;
    const _Float16* Bb = B + (long)bz * bsb;
    int m0 = by * 256;
    if (m0 + 256 > Mdim) m0 = Mdim - 256;          // overlapped last M-tile
    const int n0 = bx * 128;
    const int tid = threadIdx.x;
    const int w = tid >> 6, ln = tid & 63;
    const int wm = w >> 1, wn = w & 1;

    const int srow = tid >> 2;                       // 0..63 row within issue
    const int schunk = (tid & 3) ^ ((tid >> 3) & 3); // src chunk = dest ^ f(row)
    const _Float16* pA = Ab + (long)(m0 + srow) * lda + schunk * 8;
    const _Float16* pB = Bb + (long)(n0 + srow) * ldb + schunk * 8;
    const long lda64 = (long)64 * lda, ldb64 = (long)64 * ldb;
    const int sdw = w * 512;                         // wave-uniform dest (halfs)

    const int soff = ((ln >> 4) ^ ((ln >> 1) & 3)) * 8;
    int aoff[8], boff[4];
    #pragma unroll
    for (int mi = 0; mi < 8; ++mi)
        aoff[mi] = (wm * 128 + mi * 16 + (ln & 15)) * 32 + soff;
    #pragma unroll
    for (int ni = 0; ni < 4; ++ni)
        boff[ni] = 8192 + (wn * 64 + ni * 16 + (ln & 15)) * 32 + soff;

    floatx4 acc[8][4];
    #pragma unroll
    for (int i = 0; i < 8; ++i)
        #pragma unroll
        for (int j = 0; j < 4; ++j) acc[i][j] = (floatx4){0.f, 0.f, 0.f, 0.f};

    const int NT = K >> 5;      // BK=32

#define TILE(ISSUES, GATE)                                                   \
  {                                                                          \
    half8 af[8], bf[4];                                                      \
    _Pragma("unroll")                                                        \
    for (int mi = 0; mi < 8; ++mi)                                           \
        af[mi] = *(const half8*)&sh[cur + aoff[mi]];                         \
    _Pragma("unroll")                                                        \
    for (int ni = 0; ni < 4; ++ni)                                           \
        bf[ni] = *(const half8*)&sh[cur + boff[ni]];                         \
    ISSUES                                                                   \
    __builtin_amdgcn_sched_barrier(0);                                       \
    __builtin_amdgcn_s_barrier();                                            \
    asm volatile("s_waitcnt lgkmcnt(0)" ::: "memory");                       \
    __builtin_amdgcn_sched_barrier(0);                                       \
    __builtin_amdgcn_s_setprio(1);                                           \
    _Pragma("unroll")                                                        \
    for (int ni = 0; ni < 4; ++ni)                                           \
        _Pragma("unroll")                                                    \
        for (int mi = 0; mi < 8; ++mi)                                       \
            acc[mi][ni] = MFMA_(af[mi], bf[ni], acc[mi][ni]);                \
    __builtin_amdgcn_s_setprio(0);                                           \
    __builtin_amdgcn_sched_barrier(0);                                       \
    GATE;                                                                    \
    __builtin_amdgcn_s_barrier();                                            \
    __builtin_amdgcn_sched_barrier(0);                                       \
  }

    // ---- prologue: stage tile0 -> buf0, tile1 -> buf1 ----
    #pragma unroll
    for (int i = 0; i < 4; ++i) gload16(pA + i * lda64, &sh[i * 2048 + sdw]);
    #pragma unroll
    for (int i = 0; i < 2; ++i) gload16(pB + i * ldb64, &sh[8192 + i * 2048 + sdw]);
    #pragma unroll
    for (int i = 0; i < 4; ++i) gload16(pA + 32 + i * lda64, &sh[12288 + i * 2048 + sdw]);
    #pragma unroll
    for (int i = 0; i < 2; ++i) gload16(pB + 32 + i * ldb64, &sh[20480 + i * 2048 + sdw]);
    VM6;   // t0's 6 done; t1's 6 in flight
    __builtin_amdgcn_sched_barrier(0);
    __builtin_amdgcn_s_barrier();
    __builtin_amdgcn_sched_barrier(0);

    int cur = 0, nxt = 12288, stg = 24576;
    const _Float16* pA_s = pA + 64;
    const _Float16* pB_s = pB + 64;

    // ---- main loop: compute tile t, stage tile t+2 into stg ----
    for (int t = 0; t < NT - 2; ++t) {
        TILE(
           gload16(pA_s,             &sh[stg + sdw]);
           gload16(pA_s + lda64,     &sh[stg + 2048 + sdw]);
           gload16(pA_s + 2 * lda64, &sh[stg + 4096 + sdw]);
           gload16(pA_s + 3 * lda64, &sh[stg + 6144 + sdw]);
           gload16(pB_s,             &sh[stg + 8192 + sdw]);
           gload16(pB_s + ldb64,     &sh[stg + 10240 + sdw]);, VM6)
        const int tmp = cur; cur = nxt; nxt = stg; stg = tmp;
        pA_s += 32; pB_s += 32;
    }
    // ---- tail: tile NT-2 (drain all), tile NT-1 ----
    TILE(, VM0)
    { const int tmp = cur; cur = nxt; nxt = stg; stg = tmp; }
    TILE(, )
#undef TILE
    __builtin_amdgcn_sched_barrier(0);

    // ---- epilogue: C/D layout col = ln&15, row = (ln>>4)*4 + reg ----
    const int cm = wm * 128 + (ln >> 4) * 4;
    const int cn = wn * 64 + (ln & 15);

    if constexpr (EPI == 0) {
        if (m0 < 1024) {   // t or p -> transposed store [L, 512]
            _Float16* T = (_Float16*)C0p + (long)bz * c0s
                          + (m0 >= 512 ? (long)LP * PPL : 0);
            const int mb = m0 & 511;
            #pragma unroll
            for (int mi = 0; mi < 8; ++mi) {
                const int gmF = m0 + cm + mi * 16;
                const float4 bv = *(const float4*)&bias[gmF];
                const int gm = mb + cm + mi * 16;
                #pragma unroll
                for (int ni = 0; ni < 4; ++ni) {
                    const int gn = n0 + cn + ni * 16;
                    union { _Float16 h[4]; uint2 u; } pk;
                    pk.h[0] = (_Float16)(acc[mi][ni][0] + bv.x);
                    pk.h[1] = (_Float16)(acc[mi][ni][1] + bv.y);
                    pk.h[2] = (_Float16)(acc[mi][ni][2] + bv.z);
                    pk.h[3] = (_Float16)(acc[mi][ni][3] + bv.w);
                    *(uint2*)&T[(long)gn * PPL + gm] = pk.u;
                }
            }
        } else {           // g: normal [512, LP] + transposed into gx2T
            _Float16* G  = (_Float16*)C1p + (long)bz * c1s;
            _Float16* GT = (_Float16*)C2p + (long)bz * c2s;
            #pragma unroll
            for (int mi = 0; mi < 8; ++mi) {
                const int gmF = m0 + cm + mi * 16;
                const float4 bv = *(const float4*)&bias[gmF];
                const int q = gmF - 1024;
                #pragma unroll
                for (int ni = 0; ni < 4; ++ni) {
                    const int gn = n0 + cn + ni * 16;
                    union { _Float16 h[4]; uint2 u; } pk;
                    pk.h[0] = (_Float16)(acc[mi][ni][0] + bv.x);
                    pk.h[1] = (_Float16)(acc[mi][ni][1] + bv.y);
                    pk.h[2] = (_Float16)(acc[mi][ni][2] + bv.z);
                    pk.h[3] = (_Float16)(acc[mi][ni][3] + bv.w);
                    *(uint2*)&GT[(long)gn * 1024 + q] = pk.u;
                    const bool ok = gn < LSZ;   // keep pad cols of g zero
                    G[(long)(q + 0) * LP + gn] = ok ? pk.h[0] : (_Float16)0.f;
                    G[(long)(q + 1) * LP + gn] = ok ? pk.h[1] : (_Float16)0.f;
                    G[(long)(q + 2) * LP + gn] = ok ? pk.h[2] : (_Float16)0.f;
                    G[(long)(q + 3) * LP + gn] = ok ? pk.h[3] : (_Float16)0.f;
                }
            }
        }
    } else {                            // EPI 3: y fp16 + bias
        _Float16* C = (_Float16*)C0p + (long)bz * c0s;
        #pragma unroll
        for (int mi = 0; mi < 8; ++mi) {
            const int gmF = m0 + cm + mi * 16;
            const float4 bv = *(const float4*)&bias[gmF];
            #pragma unroll
            for (int ni = 0; ni < 4; ++ni) {
                const int gn = n0 + cn + ni * 16;
                C[(long)(gmF + 0) * LP + gn] = (_Float16)(acc[mi][ni][0] + bv.x);
                C[(long)(gmF + 1) * LP + gn] = (_Float16)(acc[mi][ni][1] + bv.y);
                C[(long)(gmF + 2) * LP + gn] = (_Float16)(acc[mi][ni][2] + bv.z);
                C[(long)(gmF + 3) * LP + gn] = (_Float16)(acc[mi][ni][3] + bv.w);
            }
        }
    }
}

// =====================================================================
// hgemm8w: 8-wave variant (round-13, G2): same 256x128 tile / 72KB 3-buf /
//  counted-vmcnt schedule, 512 threads = 8 waves (4M x 2N), per-wave 64x64.
//  2 blocks/CU -> 4 waves/SIMD. Gate vmcnt(3); tail drains 0. Emits att fp16.
// =====================================================================
__global__ __launch_bounds__(512, 4)
void hgemm8w(const _Float16* __restrict__ A, long asb, int lda,
             const _Float16* __restrict__ B, long bsb, int ldb,
             void* __restrict__ C0p, long c0s, int nx, int Mdim, int K)
{
    __shared__ __align__(16) _Float16 sh[36864];   // 72KB: 3 bufs x 12288 halfs
    const int wid = blockIdx.x;
    const int bz  = wid & 7;
    const int rr  = wid >> 3;
    const int bx  = rr % nx;
    const int by  = rr / nx;

    const _Float16* Ab = A + (long)bz * asb;
    const _Float16* Bb = B + (long)bz * bsb;
    int m0 = by * 256;
    if (m0 + 256 > Mdim) m0 = Mdim - 256;
    const int n0 = bx * 128;
    const int tid = threadIdx.x;
    const int w = tid >> 6, ln = tid & 63;
    const int wm = w >> 1, wn = w & 1;             // 4M x 2N

    const int srow = tid >> 2;                       // 0..127
    const int schunk = (tid & 3) ^ ((tid >> 3) & 3); // dest ^ f(row)
    const _Float16* pA = Ab + (long)(m0 + srow) * lda + schunk * 8;
    const _Float16* pB = Bb + (long)(n0 + srow) * ldb + schunk * 8;
    const long lda128 = (long)128 * lda;
    const int sdw = w * 512;                         // wave-uniform dest (halfs)

    const int soff = ((ln >> 4) ^ ((ln >> 1) & 3)) * 8;
    int aoff[4], boff[4];
    #pragma unroll
    for (int mi = 0; mi < 4; ++mi)
        aoff[mi] = (wm * 64 + mi * 16 + (ln & 15)) * 32 + soff;
    #pragma unroll
    for (int ni = 0; ni < 4; ++ni)
        boff[ni] = 8192 + (wn * 64 + ni * 16 + (ln & 15)) * 32 + soff;

    floatx4 acc[4][4];
    #pragma unroll
    for (int i = 0; i < 4; ++i)
        #pragma unroll
        for (int j = 0; j < 4; ++j) acc[i][j] = (floatx4){0.f, 0.f, 0.f, 0.f};

    const int NT = K >> 5;

#define STG3(koff, BASE)                                                     \
    gload16(pA + (koff),          &sh[(BASE) + sdw]);                        \
    gload16(pA + (koff) + lda128, &sh[(BASE) + 4096 + sdw]);                 \
    gload16(pB + (koff),          &sh[(BASE) + 8192 + sdw]);

#define TILEW(ISSUES, GATE)                                                  \
  {                                                                          \
    half8 af[4], bf[4];                                                      \
    _Pragma("unroll")                                                        \
    for (int mi = 0; mi < 4; ++mi)                                           \
        af[mi] = *(const half8*)&sh[cur + aoff[mi]];                         \
    _Pragma("unroll")                                                        \
    for (int ni = 0; ni < 4; ++ni)                                           \
        bf[ni] = *(const half8*)&sh[cur + boff[ni]];                         \
    ISSUES                                                                   \
    __builtin_amdgcn_sched_barrier(0);                                       \
    __builtin_amdgcn_s_barrier();                                            \
    asm volatile("s_waitcnt lgkmcnt(0)" ::: "memory");                       \
    __builtin_amdgcn_sched_barrier(0);                                       \
    __builtin_amdgcn_s_setprio(1);                                           \
    _Pragma("unroll")                                                        \
    for (int ni = 0; ni < 4; ++ni)                                           \
        _Pragma("unroll")                                                    \
        for (int mi = 0; mi < 4; ++mi)                                       \
            acc[mi][ni] = MFMA_(af[mi], bf[ni], acc[mi][ni]);                \
    __builtin_amdgcn_s_setprio(0);                                           \
    __builtin_amdgcn_sched_barrier(0);                                       \
    GATE;                                                                    \
    __builtin_amdgcn_s_barrier();                                            \
    __builtin_amdgcn_sched_barrier(0);                                       \
  }

    STG3(0, 0)
    STG3(32, 12288)
    VM3;
    __builtin_amdgcn_sched_barrier(0);
    __builtin_amdgcn_s_barrier();
    __builtin_amdgcn_sched_barrier(0);

    int cur = 0, nxt = 12288, stg = 24576;

    for (int t = 0; t < NT - 2; ++t) {
        TILEW(STG3((t + 2) * 32, stg), VM3)
        const int tmp = cur; cur = nxt; nxt = stg; stg = tmp;
    }
    TILEW(, VM0)
    { const int tmp = cur; cur = nxt; nxt = stg; stg = tmp; }
    TILEW(, )
#undef TILEW
#undef STG3
    __builtin_amdgcn_sched_barrier(0);

    // ---- epilogue: att fp16 [LP halfs pitch] ----
    const int cm = wm * 64 + (ln >> 4) * 4;
    const int cn = wn * 64 + (ln & 15);
    _Float16* C = (_Float16*)C0p + (long)bz * c0s;
    #pragma unroll
    for (int mi = 0; mi < 4; ++mi) {
        const int gm = m0 + cm + mi * 16;
        #pragma unroll
        for (int ni = 0; ni < 4; ++ni) {
            const int gn = n0 + cn + ni * 16;
            #pragma unroll
            for (int j = 0; j < 4; ++j)
                C[(long)(gm + j) * LP + gn] = (_Float16)acc[mi][ni][j];
        }
    }
}

// =====================================================================
// hgemm128: 128x128-tile GEMM for G3 (N=512), round-8/12 proven, K=1568.
//  3 bufs x 16KB = 48KB -> 3 blocks/CU; vmcnt(4) counted gate.
//  Output: x2T fp16 into gx2T[:, 512:1024].
// =====================================================================
__global__ __launch_bounds__(256, 3)
void hgemm128(const _Float16* __restrict__ A, long asb, int lda,
              const _Float16* __restrict__ B, long bsb, int ldb,
              void* __restrict__ C0p, long c0s, int nx, int K)
{
    __shared__ __align__(16) _Float16 sh[24576];   // 48KB: 3 bufs x 8192 halfs
    const int wid = blockIdx.x;
    const int bz  = wid & 7;
    const int rr  = wid >> 3;
    const int bx  = rr % nx;
    const int by  = rr / nx;

    const _Float16* Ab = A + (long)bz * asb;
    const _Float16* Bb = B + (long)bz * bsb;
    const int m0 = by * 128;
    const int n0 = bx * 128;
    const int tid = threadIdx.x;
    const int w = tid >> 6, ln = tid & 63;
    const int wm = w >> 1, wn = w & 1;

    const int srow = tid >> 2;
    const int schunk = (tid & 3) ^ ((tid >> 3) & 3);
    const _Float16* pA = Ab + (long)(m0 + srow) * lda + schunk * 8;
    const _Float16* pB = Bb + (long)(n0 + srow) * ldb + schunk * 8;
    const long lda64 = (long)64 * lda, ldb64 = (long)64 * ldb;
    const int sdw = w * 512;

    const int soff = ((ln >> 4) ^ ((ln >> 1) & 3)) * 8;
    int aoff[4], boff[4];
    #pragma unroll
    for (int mi = 0; mi < 4; ++mi)
        aoff[mi] = (wm * 64 + mi * 16 + (ln & 15)) * 32 + soff;
    #pragma unroll
    for (int ni = 0; ni < 4; ++ni)
        boff[ni] = 4096 + (wn * 64 + ni * 16 + (ln & 15)) * 32 + soff;

    floatx4 acc[4][4];
    #pragma unroll
    for (int i = 0; i < 4; ++i)
        #pragma unroll
        for (int j = 0; j < 4; ++j) acc[i][j] = (floatx4){0.f, 0.f, 0.f, 0.f};

    const int NT = K >> 5;   // 49 for K=1568

#define TILE1(ISSUES, GATE)                                                  \
  {                                                                          \
    half8 af[4], bf[4];                                                      \
    _Pragma("unroll")                                                        \
    for (int mi = 0; mi < 4; ++mi)                                           \
        af[mi] = *(const half8*)&sh[cur + aoff[mi]];                         \
    _Pragma("unroll")                                                        \
    for (int ni = 0; ni < 4; ++ni)                                           \
        bf[ni] = *(const half8*)&sh[cur + boff[ni]];                         \
    ISSUES                                                                   \
    __builtin_amdgcn_sched_barrier(0);                                       \
    __builtin_amdgcn_s_barrier();                                            \
    asm volatile("s_waitcnt lgkmcnt(0)" ::: "memory");                       \
    __builtin_amdgcn_sched_barrier(0);                                       \
    __builtin_amdgcn_s_setprio(1);                                           \
    _Pragma("unroll")                                                        \
    for (int ni = 0; ni < 4; ++ni)                                           \
        _Pragma("unroll")                                                    \
        for (int mi = 0; mi < 4; ++mi)                                       \
            acc[mi][ni] = MFMA_(af[mi], bf[ni], acc[mi][ni]);                \
    __builtin_amdgcn_s_setprio(0);                                           \
    __builtin_amdgcn_sched_barrier(0);                                       \
    GATE;                                                                    \
    __builtin_amdgcn_s_barrier();                                            \
    __builtin_amdgcn_sched_barrier(0);                                       \
  }

    // ---- prologue: stage tile0 -> buf0, tile1 -> buf1 (4 issues each) ----
    gload16(pA,              &sh[sdw]);
    gload16(pA + lda64,      &sh[2048 + sdw]);
    gload16(pB,              &sh[4096 + sdw]);
    gload16(pB + ldb64,      &sh[6144 + sdw]);
    gload16(pA + 32,         &sh[8192 + sdw]);
    gload16(pA + 32 + lda64, &sh[10240 + sdw]);
    gload16(pB + 32,         &sh[12288 + sdw]);
    gload16(pB + 32 + ldb64, &sh[14336 + sdw]);
    VM4;   // t0's 4 done; t1's 4 in flight
    __builtin_amdgcn_sched_barrier(0);
    __builtin_amdgcn_s_barrier();
    __builtin_amdgcn_sched_barrier(0);

    int cur = 0, nxt = 8192, stg = 16384;
    const _Float16* pA_s = pA + 64;
    const _Float16* pB_s = pB + 64;

    for (int t = 0; t < NT - 2; ++t) {
        TILE1(
           gload16(pA_s,         &sh[stg + sdw]);
           gload16(pA_s + lda64, &sh[stg + 2048 + sdw]);
           gload16(pB_s,         &sh[stg + 4096 + sdw]);
           gload16(pB_s + ldb64, &sh[stg + 6144 + sdw]);, VM4)
        const int tmp = cur; cur = nxt; nxt = stg; stg = tmp;
        pA_s += 32; pB_s += 32;
    }
    TILE1(, VM0)
    { const int tmp = cur; cur = nxt; nxt = stg; stg = tmp; }
    TILE1(, )
#undef TILE1
    __builtin_amdgcn_sched_barrier(0);

    const int cm = wm * 64 + (ln >> 4) * 4;
    const int cn = wn * 64 + (ln & 15);
    _Float16* C = (_Float16*)C0p + (long)bz * c0s + 512;   // cols 512..1023
    #pragma unroll
    for (int mi = 0; mi < 4; ++mi) {
        const int gm = m0 + cm + mi * 16;
        #pragma unroll
        for (int ni = 0; ni < 4; ++ni) {
            const int gn = n0 + cn + ni * 16;
            #pragma unroll
            for (int j = 0; j < 4; ++j)
                C[(long)(gm + j) * 1024 + gn] = (_Float16)acc[mi][ni][j];
        }
    }
}

// ---- weight converts ----
__global__ void conv_wtpg(const float* __restrict__ tw, const float* __restrict__ pw,
                          const float* __restrict__ gw, const float* __restrict__ tb,
                          const float* __restrict__ pb, const float* __restrict__ gb,
                          _Float16* __restrict__ W, float* __restrict__ btpg)
{
    const int i = blockIdx.x * 256 + threadIdx.x;     // float4 groups
    if (i < 393216) {
        const int e = i * 4;
        const int sz = 512 * 1024;
        const float* src = (e < sz) ? tw + e : ((e < 2 * sz) ? pw + e - sz : gw + e - 2 * sz);
        const float4 v = *(const float4*)src;
        union { _Float16 h[4]; uint2 u; } pk;
        pk.h[0] = (_Float16)v.x; pk.h[1] = (_Float16)v.y;
        pk.h[2] = (_Float16)v.z; pk.h[3] = (_Float16)v.w;
        *(uint2*)&W[e] = pk.u;
    }
    if (i < 512) btpg[i] = tb[i];
    else if (i < 1024) btpg[i] = pb[i - 512];
    else if (i < 1536) btpg[i] = gb[i - 1024];
}

__global__ void conv_wcat(const float* __restrict__ w1, const float* __restrict__ w2,
                          const float* __restrict__ b1, const float* __restrict__ b2,
                          _Float16* __restrict__ W, float* __restrict__ bsum)
{
    const int i = blockIdx.x * 256 + threadIdx.x;     // float4 groups
    if (i < 262144) {
        const int e = i * 4;
        const int c = e >> 10, k = e & 1023;
        const float* src = (k < 512) ? (w1 + c * 512 + k) : (w2 + c * 512 + k - 512);
        const float4 v = *(const float4*)src;
        union { _Float16 h[4]; uint2 u; } pk;
        pk.h[0] = (_Float16)v.x; pk.h[1] = (_Float16)v.y;
        pk.h[2] = (_Float16)v.z; pk.h[3] = (_Float16)v.w;
        *(uint2*)&W[e] = pk.u;
    }
    if (i < 1024) bsum[i] = b1[i] + b2[i];
}

// ---- x [b*8+n][c][hw] fp32 -> xtT [b][l=n*196+hw][c] fp16, LDS transpose ----
__global__ __launch_bounds__(256) void transpose_x(const float* __restrict__ x,
                                                   _Float16* __restrict__ xtT)
{
    __shared__ _Float16 t[128 * 201];
    const int cs = blockIdx.x * 128;
    const int n = blockIdx.y, b = blockIdx.z;
    const float* src = x + ((long)(b * 8 + n) * 1024 + cs) * 196;
    for (int i = threadIdx.x; i < 128 * 49; i += 256) {
        const int r = i / 49, ch = i % 49;
        const float4 v = *(const float4*)&src[r * 196 + ch * 4];
        _Float16* tp = &t[r * 201 + ch * 4];
        tp[0] = (_Float16)v.x; tp[1] = (_Float16)v.y;
        tp[2] = (_Float16)v.z; tp[3] = (_Float16)v.w;
    }
    __syncthreads();
    _Float16* dst = xtT + (long)b * LP * 1024 + (long)n * 196 * 1024 + cs;
    for (int i = threadIdx.x; i < 196 * 16; i += 256) {
        const int hw = i >> 4, cg = i & 15;
        union { _Float16 h[8]; uint4 u; } pk;
        #pragma unroll
        for (int j = 0; j < 8; ++j) pk.h[j] = t[(cg * 8 + j) * 201 + hw];
        *(uint4*)&dst[(long)hw * 1024 + cg * 8] = pk.u;
    }
}

// ---- softmax: att fp16 rows in place, half8-vectorized; zero-pad K-tail ----
__global__ __launch_bounds__(256) void softmax_rows(_Float16* __restrict__ att)
{
    const int blk = blockIdx.x;
    const int b = blk / LSZ, r = blk % LSZ;
    _Float16* row = att + (long)b * LP * LP + (long)r * LP;
    const int tid = threadIdx.x;
    const bool act = tid < 196;

    float v[8];
    float mx = -1e30f;
    if (act) {
        const half8 h = *(const half8*)&row[tid * 8];
        #pragma unroll
        for (int j = 0; j < 8; ++j) { v[j] = (float)h[j]; mx = fmaxf(mx, v[j]); }
    }
    __shared__ float red[256];
    red[tid] = mx; __syncthreads();
    for (int s = 128; s > 0; s >>= 1) {
        if (tid < s) red[tid] = fmaxf(red[tid], red[tid + s]);
        __syncthreads();
    }
    mx = red[0]; __syncthreads();

    float sum = 0.0f;
    if (act) {
        #pragma unroll
        for (int j = 0; j < 8; ++j) { v[j] = __expf(v[j] - mx); sum += v[j]; }
    }
    red[tid] = sum; __syncthreads();
    for (int s = 128; s > 0; s >>= 1) {
        if (tid < s) red[tid] += red[tid + s];
        __syncthreads();
    }
    const float inv = 1.0f / red[0];
    if (act) {
        union { _Float16 h[8]; uint4 u; } pk;
        #pragma unroll
        for (int j = 0; j < 8; ++j) pk.h[j] = (_Float16)(v[j] * inv);
        *(uint4*)&row[tid * 8] = pk.u;
    } else if (tid < 208) {
        union { _Float16 h[8]; uint4 u; } pk;
        #pragma unroll
        for (int j = 0; j < 8; ++j) pk.h[j] = (_Float16)0.f;
        *(uint4*)&row[tid * 8] = pk.u;
    }
}

// ---- BN stats per channel over (b, l<1568) from y fp16 [1024, LP] ----
__global__ __launch_bounds__(256)
void bn_stats(const _Float16* __restrict__ y, const float* __restrict__ gamma,
              const float* __restrict__ beta, float* __restrict__ scale,
              float* __restrict__ shift)
{
    const int c = blockIdx.x;
    const int tid = threadIdx.x;
    float s1 = 0.f, s2 = 0.f;
    for (int idx = tid; idx < 8 * 196; idx += 256) {
        const int b = idx / 196, ch = idx % 196;
        const half8 v = *(const half8*)&y[(long)b * CCH * LP + (long)c * LP + ch * 8];
        #pragma unroll
        for (int j = 0; j < 8; ++j) { const float t = (float)v[j]; s1 += t; s2 += t * t; }
    }
    __shared__ float r1[256], r2[256];
    r1[tid] = s1; r2[tid] = s2; __syncthreads();
    for (int s = 128; s > 0; s >>= 1) {
        if (tid < s) { r1[tid] += r1[tid + s]; r2[tid] += r2[tid + s]; }
        __syncthreads();
    }
    if (tid == 0) {
        const float cnt = (float)(BATCH * LSZ);
        const float mean = r1[0] / cnt;
        const float var  = r2[0] / cnt - mean * mean;
        const float istd = rsqrtf(var + BN_EPS);
        const float sc = gamma[c] * istd;
        scale[c] = sc;
        shift[c] = beta[c] - mean * sc;
    }
}

// ---- out[b,n,c,hw] = y[b,c,n*196+hw]*scale[c]+shift[c] + x[b,n,c,hw] ----
__global__ void epilogue_k(const _Float16* __restrict__ y, const float* __restrict__ x,
                           const float* __restrict__ scale, const float* __restrict__ shift,
                           float* __restrict__ out)
{
    const long i4 = (long)blockIdx.x * 256 + threadIdx.x;
    const long idx = i4 * 4;
    if (idx >= TOT) return;
    const int b  = (int)(idx / ((long)SEQn * CCH * HWSZ));
    const int r  = (int)(idx % ((long)SEQn * CCH * HWSZ));
    const int n  = r / (CCH * HWSZ);
    const int r2 = r % (CCH * HWSZ);
    const int c  = r2 / HWSZ;
    const int hw = r2 % HWSZ;
    union { _Float16 h[4]; uint2 u; } v;
    v.u = *(const uint2*)&y[(long)b * CCH * LP + (long)c * LP + n * 196 + hw];
    const float4 xv = *(const float4*)&x[idx];
    const float sc = scale[c], sh = shift[c];
    float4 o;
    o.x = (float)v.h[0] * sc + sh + xv.x;
    o.y = (float)v.h[1] * sc + sh + xv.y;
    o.z = (float)v.h[2] * sc + sh + xv.z;
    o.w = (float)v.h[3] * sc + sh + xv.w;
    *(float4*)&out[idx] = o;
}

extern "C" void kernel_launch(void* const* d_in, const int* in_sizes, int n_in,
                              void* d_out, int out_size, void* d_ws, size_t ws_size,
                              hipStream_t stream)
{
    const float* x     = (const float*)d_in[0];
    const float* t_w   = (const float*)d_in[1];
    const float* t_b   = (const float*)d_in[2];
    const float* p_w   = (const float*)d_in[3];
    const float* p_b   = (const float*)d_in[4];
    const float* g_w   = (const float*)d_in[5];
    const float* g_b   = (const float*)d_in[6];
    const float* w1_w  = (const float*)d_in[7];
    const float* w1_b  = (const float*)d_in[8];
    const float* w2_w  = (const float*)d_in[9];
    const float* w2_b  = (const float*)d_in[10];
    const float* gamma = (const float*)d_in[11];
    const float* beta  = (const float*)d_in[12];
    float* out = (float*)d_out;

    // ---- workspace layout ----
    char* wsp = (char*)d_ws;
    _Float16* Wtpg = (_Float16*)wsp;                 wsp += (long)1536 * 1024 * 2;
    _Float16* Wcat = (_Float16*)wsp;                 wsp += (long)1024 * 1024 * 2;
    float*    btpg = (float*)wsp;                    wsp += 8192;
    float*    bsum = (float*)wsp;                    wsp += 4096;
    float*    scale= (float*)wsp;                    wsp += 4096;
    float*    shift= (float*)wsp;                    wsp += 4096;
    _Float16* xtT  = (_Float16*)wsp;                 wsp += (long)BATCH * LP * 1024 * 2;
    _Float16* tTpT = (_Float16*)wsp;                 wsp += (long)BATCH * 2 * LP * 512 * 2;
    _Float16* g    = (_Float16*)wsp;                 wsp += (long)BATCH * 512 * LP * 2;
    _Float16* gx2T = (_Float16*)wsp;                 wsp += (long)BATCH * LP * 1024 * 2;
    _Float16* att  = (_Float16*)wsp;                 wsp += (long)BATCH * LP * LP * 2;
    _Float16* y    = xtT;    // alias: xtT dead after G1, G4 runs after

    const long sXT  = (long)LP * 1024;     // xtT / gx2T per-batch (halfs)
    const long sTP  = (long)2 * LP * 512;  // tTpT per-batch
    const long sG   = (long)512 * LP;
    const long sATT = (long)LP * LP;       // att per-batch (halfs)
    const long sY   = (long)CCH * LP;

    // 1) weight converts
    conv_wtpg<<<1536, 256, 0, stream>>>(t_w, p_w, g_w, t_b, p_b, g_b, Wtpg, btpg);
    conv_wcat<<<1024, 256, 0, stream>>>(w1_w, w2_w, w1_b, w2_b, Wcat, bsum);
    // 2) x -> xtT [b, l, c] fp16
    transpose_x<<<dim3(8, 8, 8), 256, 0, stream>>>(x, xtT);
    // 3) tpg projections: M=1536 (6), N=1664 (13), K=1024; grid 624 = 78x8
    hgemm8<0><<<624, 256, 0, stream>>>(
        Wtpg, 0, 1024, xtT, sXT, 1024,
        tTpT, sTP, g, sG, gx2T, sXT, btpg, 13, 1536, 1024);
    // 4) att = tT @ pT^T (fp16 out): 8-wave variant, M=1664, N=1664, K=512
    hgemm8w<<<728, 512, 0, stream>>>(
        tTpT, sTP, 512, tTpT + (long)LP * 512, sTP, 512,
        att, sATT, 13, LP, 512);
    // 5) softmax rows (fp16 in place, zero-pad K-tail)
    softmax_rows<<<BATCH * LSZ, 256, 0, stream>>>(att);
    // 6) x2T[l,q] = sum_{m<1568} att[l,m] g[q,m]: M=1664 (13), N=512 (4), K=1568
    hgemm128<<<416, 256, 0, stream>>>(
        att, sATT, LP, g, sG, LP,
        gx2T, sXT, 4, 1568);
    // 7) y = [W1|W2] @ [gT|x2T]^T + (b1+b2): M=1024 (4), N=1664 (13), K=1024
    hgemm8<3><<<416, 256, 0, stream>>>(
        Wcat, 0, 1024, gx2T, sXT, 1024,
        y, sY, nullptr, 0, nullptr, 0, bsum, 13, 1024, 1024);
    // 8) BN stats
    bn_stats<<<CCH, 256, 0, stream>>>(y, gamma, beta, scale, shift);
    // 9) BN apply + residual + layout restore
    epilogue_k<<<(int)(TOT / 4 / 256), 256, 0, stream>>>(y, x, scale, shift, out);
}